// Round 8
// baseline (195.923 us; speedup 1.0000x reference)
//
#include <hip/hip_runtime.h>

#define HW_N (512 * 512)          // pixels per image plane
#define BINS 64
#define BPI  64                   // blocks per image; 16*64 = 1024 = exactly 4 blocks/CU (all resident)
#define TPB  256
#define QPB  ((HW_N / 4) / BPI)   // float4 groups per block per stream = 1024
#define ITER (QPB / TPB)          // 4 compile-time iterations -> 32 gray floats in registers/thread
#define MAXB 16

// All cross-block state. Zeroed by k_init; accessed ONLY via RELAXED device-scope atomics.
// Ordering comes from: publish-atomics -> __syncthreads (drains vmcnt -> complete at the
// coherent point) -> relaxed done-counter RMW; coherent-point serialization does the rest.
// NO release/acquire/fence anywhere (rounds 2/5/6 proved those are invalidation storms).
struct Ctrl {
    unsigned int doneA[MAXB];        // phase-A completion per image
    unsigned int doneB[MAXB];        // phase-B (hist) completion per image
    unsigned int done2;              // per-image tails completed
    unsigned int pad[3];
    unsigned int mm[MAXB][4];        // {ord(-mnx), ord(mxx), ord(-mny), ord(mxy)} via atomicMax
    double sums[MAXB][6];            // channel sums via atomicAdd(double)
    double klacc, cbacc;             // loss accumulators
    unsigned int hist[MAXB][2][BINS];
};

__device__ __forceinline__ unsigned int f2ord(float f) {
    unsigned int u = __float_as_uint(f);
    return (u & 0x80000000u) ? ~u : (u | 0x80000000u);   // monotone; any finite float > 0u
}
__device__ __forceinline__ float ord2f(unsigned int u) {
    u = (u & 0x80000000u) ? (u ^ 0x80000000u) : ~u;
    return __uint_as_float(u);
}

__device__ __forceinline__ float grayf(float r, float g, float b) {
    return 0.299f * r + 0.587f * g + 0.114f * b;
}

__device__ __forceinline__ double waveSumD(double v) {
#pragma unroll
    for (int o = 32; o > 0; o >>= 1) v += __shfl_down(v, o);
    return v;
}
__device__ __forceinline__ float waveMinAll(float v) {
#pragma unroll
    for (int o = 32; o > 0; o >>= 1) v = fminf(v, __shfl_xor(v, o));
    return v;
}
__device__ __forceinline__ float waveMaxAll(float v) {
#pragma unroll
    for (int o = 32; o > 0; o >>= 1) v = fmaxf(v, __shfl_xor(v, o));
    return v;
}

// tiny init (kernel boundary = the only fence we need before the fused kernel's atomics)
__global__ void k_init(unsigned int* w) {
    const int n = (int)(sizeof(Ctrl) / 4);
    for (int i = threadIdx.x; i < n; i += TPB) w[i] = 0u;
}

__global__ __launch_bounds__(TPB, 4) void k_fused(const float* __restrict__ x,
                                                  const float* __restrict__ y,
                                                  Ctrl* __restrict__ ctrl,
                                                  float* __restrict__ out, int B) {
    const int tid  = threadIdx.x;
    const int blk  = blockIdx.x;
    const int b    = blk / BPI;
    const int sub  = blk % BPI;
    const int wave = tid >> 6;
    const int lane = tid & 63;

    const int q0 = sub * QPB;
    const size_t base = (size_t)b * 3 * HW_N;
    const float4* xr = (const float4*)(x + base);
    const float4* xg = (const float4*)(x + base + HW_N);
    const float4* xb = (const float4*)(x + base + 2 * HW_N);
    const float4* yr = (const float4*)(y + base);
    const float4* yg = (const float4*)(y + base + HW_N);
    const float4* yb = (const float4*)(y + base + 2 * HW_N);

    // ------------- phase A: single streaming pass; grays stay in registers -------------
    float s0 = 0.f, s1 = 0.f, s2 = 0.f;
    float t0 = 0.f, t1 = 0.f, t2 = 0.f;
    float mnx = 3.4e38f, mxx = -3.4e38f;
    float mny = 3.4e38f, mxy = -3.4e38f;
    float4 gxv[ITER], gyv[ITER];            // static indexing only -> stays in VGPRs

#pragma unroll
    for (int i = 0; i < ITER; i++) {
        const int q = q0 + tid + i * TPB;
        float4 r = xr[q], g = xg[q], bl = xb[q];
        s0 += (r.x + r.y) + (r.z + r.w);
        s1 += (g.x + g.y) + (g.z + g.w);
        s2 += (bl.x + bl.y) + (bl.z + bl.w);
        {
            float g0 = grayf(r.x, g.x, bl.x), g1 = grayf(r.y, g.y, bl.y);
            float g2 = grayf(r.z, g.z, bl.z), g3 = grayf(r.w, g.w, bl.w);
            mnx = fminf(mnx, fminf(fminf(g0, g1), fminf(g2, g3)));
            mxx = fmaxf(mxx, fmaxf(fmaxf(g0, g1), fmaxf(g2, g3)));
            gxv[i] = make_float4(g0, g1, g2, g3);
        }
        r = yr[q]; g = yg[q]; bl = yb[q];
        t0 += (r.x + r.y) + (r.z + r.w);
        t1 += (g.x + g.y) + (g.z + g.w);
        t2 += (bl.x + bl.y) + (bl.z + bl.w);
        {
            float g0 = grayf(r.x, g.x, bl.x), g1 = grayf(r.y, g.y, bl.y);
            float g2 = grayf(r.z, g.z, bl.z), g3 = grayf(r.w, g.w, bl.w);
            mny = fminf(mny, fminf(fminf(g0, g1), fminf(g2, g3)));
            mxy = fmaxf(mxy, fmaxf(fmaxf(g0, g1), fmaxf(g2, g3)));
            gyv[i] = make_float4(g0, g1, g2, g3);
        }
    }

    // zero wave-private LDS hists (ordered before phase B by the barriers below)
    __shared__ unsigned int lh[8][BINS];    // [2 srcs][4 waves][64 bins]
    for (int i = tid; i < 8 * BINS; i += TPB) ((unsigned int*)lh)[i] = 0u;

    __shared__ double shs[6][TPB / 64];
    __shared__ float  shmn[2][TPB / 64];
    __shared__ float  shmx[2][TPB / 64];
    __shared__ float  bc[4];
    __shared__ unsigned int s_li;

    double d;
    d = waveSumD((double)s0); if (!lane) shs[0][wave] = d;
    d = waveSumD((double)s1); if (!lane) shs[1][wave] = d;
    d = waveSumD((double)s2); if (!lane) shs[2][wave] = d;
    d = waveSumD((double)t0); if (!lane) shs[3][wave] = d;
    d = waveSumD((double)t1); if (!lane) shs[4][wave] = d;
    d = waveSumD((double)t2); if (!lane) shs[5][wave] = d;
    float f;
    f = waveMinAll(mnx); if (!lane) shmn[0][wave] = f;
    f = waveMinAll(mny); if (!lane) shmn[1][wave] = f;
    f = waveMaxAll(mxx); if (!lane) shmx[0][wave] = f;
    f = waveMaxAll(mxy); if (!lane) shmx[1][wave] = f;
    __syncthreads();

    // publish block partials (RELAXED device-scope atomics -> coherent point, no cache ops)
    if (tid == 0) {
        atomicAdd(&ctrl->sums[b][0], shs[0][0] + shs[0][1] + shs[0][2] + shs[0][3]);
        atomicAdd(&ctrl->sums[b][1], shs[1][0] + shs[1][1] + shs[1][2] + shs[1][3]);
        atomicAdd(&ctrl->sums[b][2], shs[2][0] + shs[2][1] + shs[2][2] + shs[2][3]);
        atomicAdd(&ctrl->sums[b][3], shs[3][0] + shs[3][1] + shs[3][2] + shs[3][3]);
        atomicAdd(&ctrl->sums[b][4], shs[4][0] + shs[4][1] + shs[4][2] + shs[4][3]);
        atomicAdd(&ctrl->sums[b][5], shs[5][0] + shs[5][1] + shs[5][2] + shs[5][3]);
        float a;
        a = fminf(fminf(shmn[0][0], shmn[0][1]), fminf(shmn[0][2], shmn[0][3]));
        atomicMax(&ctrl->mm[b][0], f2ord(-a));        // min as max of ord(-v); 0-init safe
        a = fmaxf(fmaxf(shmx[0][0], shmx[0][1]), fmaxf(shmx[0][2], shmx[0][3]));
        atomicMax(&ctrl->mm[b][1], f2ord(a));
        a = fminf(fminf(shmn[1][0], shmn[1][1]), fminf(shmn[1][2], shmn[1][3]));
        atomicMax(&ctrl->mm[b][2], f2ord(-a));
        a = fmaxf(fmaxf(shmx[1][0], shmx[1][1]), fmaxf(shmx[1][2], shmx[1][3]));
        atomicMax(&ctrl->mm[b][3], f2ord(a));
    }
    __syncthreads();   // drains tid0's vmcnt: all publishes COMPLETE at the coherent point

    // per-image rendezvous: relaxed RMW + RELAXED-load poll (no acquire -> no invalidates).
    // All 1024 blocks are resident (4/CU exactly), so every sibling publishes: no deadlock.
    if (tid == 0) {
        __hip_atomic_fetch_add(&ctrl->doneA[b], 1u, __ATOMIC_RELAXED, __HIP_MEMORY_SCOPE_AGENT);
        while (__hip_atomic_load(&ctrl->doneA[b], __ATOMIC_RELAXED,
                                 __HIP_MEMORY_SCOPE_AGENT) < (unsigned)BPI)
            __builtin_amdgcn_s_sleep(8);
        bc[0] = -ord2f(__hip_atomic_load(&ctrl->mm[b][0], __ATOMIC_RELAXED, __HIP_MEMORY_SCOPE_AGENT));
        bc[1] =  ord2f(__hip_atomic_load(&ctrl->mm[b][1], __ATOMIC_RELAXED, __HIP_MEMORY_SCOPE_AGENT));
        bc[2] = -ord2f(__hip_atomic_load(&ctrl->mm[b][2], __ATOMIC_RELAXED, __HIP_MEMORY_SCOPE_AGENT));
        bc[3] =  ord2f(__hip_atomic_load(&ctrl->mm[b][3], __ATOMIC_RELAXED, __HIP_MEMORY_SCOPE_AGENT));
    }
    __syncthreads();

    const float imnx = bc[0], imxx = bc[1], imny = bc[2], imxy = bc[3];
    const float rgx = (imxx > imnx) ? (imxx - imnx) : 1.0f;
    const float rgy = (imxy > imny) ? (imxy - imny) : 1.0f;

    // ------------- phase B: histogram straight from registers (zero loads) -------------
    unsigned int* hx = lh[wave];
    unsigned int* hy = lh[4 + wave];

#pragma unroll
    for (int i = 0; i < ITER; i++) {
        {
            const float g[4] = { gxv[i].x, gxv[i].y, gxv[i].z, gxv[i].w };
#pragma unroll
            for (int j = 0; j < 4; j++) {
                float t = ((g[j] - imnx) / rgx) * 63.0f;   // match ref: div, *63, trunc, clip
                int id = (int)t;
                id = id < 0 ? 0 : (id > 63 ? 63 : id);
                atomicAdd(&hx[id], 1u);
            }
        }
        {
            const float g[4] = { gyv[i].x, gyv[i].y, gyv[i].z, gyv[i].w };
#pragma unroll
            for (int j = 0; j < 4; j++) {
                float t = ((g[j] - imny) / rgy) * 63.0f;
                int id = (int)t;
                id = id < 0 ? 0 : (id > 63 ? 63 : id);
                atomicAdd(&hy[id], 1u);
            }
        }
    }
    __syncthreads();

    // merge wave-hists -> per-image global hist (relaxed device atomics)
    for (int i = tid; i < 2 * BINS; i += TPB) {
        const int src = i >> 6, bin = i & 63;
        unsigned int v = lh[src * 4 + 0][bin] + lh[src * 4 + 1][bin] +
                         lh[src * 4 + 2][bin] + lh[src * 4 + 3][bin];
        if (v) atomicAdd(&ctrl->hist[b][src][bin], v);
    }
    __syncthreads();   // drain hist atomics -> complete at coherent point

    // last-block-done per image (no waiting): round-7-proven pattern
    if (tid == 0) {
        unsigned int old = __hip_atomic_fetch_add(&ctrl->doneB[b], 1u,
                                                  __ATOMIC_RELAXED, __HIP_MEMORY_SCOPE_AGENT);
        s_li = (old == BPI - 1) ? 1u : 0u;
    }
    __syncthreads();
    if (!s_li) return;

    // ------------- per-image tail (one block per image, overlapped) -------------
    const float invN = 1.0f / (float)HW_N;   // 2^-18, exact
    const bool vldx = imxx > imnx;
    const bool vldy = imxy > imny;

    if (tid < 64) {
        // wave 0: KL over the 64 bins
        const unsigned int cx = __hip_atomic_load(&ctrl->hist[b][0][tid],
                                                  __ATOMIC_RELAXED, __HIP_MEMORY_SCOPE_AGENT);
        const unsigned int cy = __hip_atomic_load(&ctrl->hist[b][1][tid],
                                                  __ATOMIC_RELAXED, __HIP_MEMORY_SCOPE_AGENT);
        const float xh = vldx ? (float)cx * invN : (1.0f / BINS);
        const float yh = vldy ? (float)cy * invN : (1.0f / BINS);
        const float log_in = logf(xh + 1e-8f);
        const float ylogy = (yh > 0.0f) ? yh * logf(yh) : 0.0f;
        double term = (double)ylogy - (double)yh * (double)log_in;
        term = waveSumD(term);
        if (tid == 0) atomicAdd(&ctrl->klacc, term);
    } else if (tid == 64) {
        // one lane: color balance from the accumulated per-image sums
        double sv[6];
#pragma unroll
        for (int k = 0; k < 6; k++)
            sv[k] = __hip_atomic_load(&ctrl->sums[b][k], __ATOMIC_RELAXED,
                                      __HIP_MEMORY_SCOPE_AGENT);
        const double N = (double)HW_N;
        const double dx = (sv[0] + sv[1] + sv[2]) / N + 1e-8;
        const double dy = (sv[3] + sv[4] + sv[5]) / N + 1e-8;
        double cbt = 0.0;
        cbt += fabs((sv[0] / N) / dx - (sv[3] / N) / dy);
        cbt += fabs((sv[1] / N) / dx - (sv[4] / N) / dy);
        cbt += fabs((sv[2] / N) / dx - (sv[5] / N) / dy);
        atomicAdd(&ctrl->cbacc, cbt);
    }
    __syncthreads();   // drain klacc/cbacc atomics before the global done counter

    if (tid == 0) {
        unsigned int old2 = __hip_atomic_fetch_add(&ctrl->done2, 1u,
                                                   __ATOMIC_RELAXED, __HIP_MEMORY_SCOPE_AGENT);
        if (old2 == (unsigned)(B - 1)) {
            const double K = __hip_atomic_load(&ctrl->klacc, __ATOMIC_RELAXED,
                                               __HIP_MEMORY_SCOPE_AGENT);
            const double C = __hip_atomic_load(&ctrl->cbacc, __ATOMIC_RELAXED,
                                               __HIP_MEMORY_SCOPE_AGENT);
            out[0] = (float)(10.0 * (C / (double)(B * 3) + K / (double)B));
        }
    }
}

extern "C" void kernel_launch(void* const* d_in, const int* in_sizes, int n_in,
                              void* d_out, int out_size, void* d_ws, size_t ws_size,
                              hipStream_t stream) {
    const float* x = (const float*)d_in[0];
    const float* y = (const float*)d_in[1];
    float* out = (float*)d_out;
    const int B = in_sizes[0] / (3 * HW_N);   // 16

    Ctrl* ctrl = (Ctrl*)d_ws;                 // ~9.4 KiB

    k_init<<<1, TPB, 0, stream>>>((unsigned int*)d_ws);
    k_fused<<<B * BPI, TPB, 0, stream>>>(x, y, ctrl, out, B);
}